// Round 14
// baseline (638.725 us; speedup 1.0000x reference)
//
#include <hip/hip_runtime.h>
#include <math.h>

#define B_   512
#define N_   193
#define D_   512
#define E_   2048
#define KTOK 96
#define H_   1024
#define M1   (B_ * KTOK)      // 49152
#define KGD  (KTOK * 4)       // 384

typedef _Float16 half8 __attribute__((ext_vector_type(8)));
typedef _Float16 half4v __attribute__((ext_vector_type(4)));
typedef float floatx4 __attribute__((ext_vector_type(4)));

// async global->LDS, 16B per lane; LDS dest = wave-uniform base + lane*16
__device__ __forceinline__ void gll16(const _Float16* g, _Float16* l) {
    __builtin_amdgcn_global_load_lds(
        (const __attribute__((address_space(1))) unsigned int*)(const void*)g,
        (__attribute__((address_space(3))) unsigned int*)(void*)l, 16, 0, 0);
}

// ---------------- K0: zero BN stats ----------------
__global__ void zero_stats_kernel(double* stats) {
    int i = blockIdx.x * 256 + threadIdx.x;
    if (i < 2 * H_) stats[i] = 0.0;
}

// ---------------- K1: exact stable top-k (rank count) ----------------
__global__ void topk_kernel(const float* __restrict__ atten, int* __restrict__ idx) {
    __shared__ float s[N_];
    int b = blockIdx.x;
    const float* row = atten + (size_t)b * N_ * N_;   // atten[b, 0, :]
    for (int i = threadIdx.x; i < N_; i += blockDim.x)
        s[i] = (i == 0) ? -1.0f : row[i];
    __syncthreads();
    for (int i = threadIdx.x; i < N_; i += blockDim.x) {
        float v = s[i];
        int rank = 0;
        for (int j = 0; j < N_; ++j) {
            float u = s[j];
            rank += (u > v) || (u == v && j < i);
        }
        if (rank < KTOK) idx[b * KTOK + rank] = i;
    }
}

// ---------------- K2: gather + l2norm -> Xh (f16) + dyn-proj stage 1 (Y) ----------------
__global__ __launch_bounds__(256) void gather_kernel(
        const float* __restrict__ base, const int* __restrict__ idx,
        const float* __restrict__ W_dyn, const float* __restrict__ b_dyn,
        _Float16* __restrict__ Xh, float* __restrict__ Y) {
    int ln = threadIdx.x & 63, wv = threadIdx.x >> 6;
    int rowid = blockIdx.x * 4 + wv;        // 0..49151 = b*96 + t
    int b = rowid / KTOK, t = rowid - b * KTOK;
    int tok = idx[rowid];
    const float4* src = (const float4*)(base + ((size_t)b * N_ + tok) * D_);
    float4 v0 = src[ln * 2], v1 = src[ln * 2 + 1];

    float vals[5];
    vals[0] = v0.x * v0.x + v0.y * v0.y + v0.z * v0.z + v0.w * v0.w
            + v1.x * v1.x + v1.y * v1.y + v1.z * v1.z + v1.w * v1.w;
#pragma unroll
    for (int r = 0; r < 4; ++r) {
        const float4* wr = (const float4*)(W_dyn + r * D_);
        float4 w0 = wr[ln * 2], w1 = wr[ln * 2 + 1];
        vals[1 + r] = v0.x * w0.x + v0.y * w0.y + v0.z * w0.z + v0.w * w0.w
                    + v1.x * w1.x + v1.y * w1.y + v1.z * w1.z + v1.w * w1.w;
    }
#pragma unroll
    for (int c = 0; c < 5; ++c)
#pragma unroll
        for (int o = 32; o > 0; o >>= 1) vals[c] += __shfl_xor(vals[c], o, 64);

    float inv = 1.0f / (sqrtf(vals[0]) + 1e-8f);
    half8 o8;
    o8[0] = (_Float16)(v0.x * inv); o8[1] = (_Float16)(v0.y * inv);
    o8[2] = (_Float16)(v0.z * inv); o8[3] = (_Float16)(v0.w * inv);
    o8[4] = (_Float16)(v1.x * inv); o8[5] = (_Float16)(v1.y * inv);
    o8[6] = (_Float16)(v1.z * inv); o8[7] = (_Float16)(v1.w * inv);
    *(half8*)&Xh[(size_t)rowid * D_ + ln * 8] = o8;
    if (ln == 0) {
        int g = b >> 2;
        int n = (b & 3) * KTOK + t;
#pragma unroll
        for (int r = 0; r < 4; ++r)
            Y[(size_t)(g * 4 + r) * KGD + n] = vals[1 + r] + b_dyn[r];
    }
}

// ---------------- K3: new_feats = l2norm(Y @ W_lin^T + b_lin) (fp32, small) ----------------
__global__ __launch_bounds__(256) void newfeat_kernel(
        const float* __restrict__ Y, const float* __restrict__ W_lin,
        const float* __restrict__ b_lin, float* __restrict__ NF) {
    __shared__ float sy[4][KGD];
    __shared__ float red[4][4];
    __shared__ float tot[4];
    int b0 = blockIdx.x * 4;
    int tid = threadIdx.x;
    for (int l = tid; l < 4 * KGD; l += 256)
        sy[l / KGD][l % KGD] = Y[(size_t)b0 * KGD + l];
    __syncthreads();

    float out[4][8];
    float ssq[4] = {0.f, 0.f, 0.f, 0.f};
#pragma unroll
    for (int q = 0; q < 8; ++q) {
        int o = tid + 256 * q;
        float a0 = 0.f, a1 = 0.f, a2 = 0.f, a3 = 0.f;
        const float4* wr = (const float4*)(W_lin + (size_t)o * KGD);
        for (int i4 = 0; i4 < KGD / 4; ++i4) {
            float4 w  = wr[i4];
            float4 s0 = *(const float4*)&sy[0][i4 * 4];
            float4 s1 = *(const float4*)&sy[1][i4 * 4];
            float4 s2 = *(const float4*)&sy[2][i4 * 4];
            float4 s3 = *(const float4*)&sy[3][i4 * 4];
            a0 += w.x * s0.x + w.y * s0.y + w.z * s0.z + w.w * s0.w;
            a1 += w.x * s1.x + w.y * s1.y + w.z * s1.z + w.w * s1.w;
            a2 += w.x * s2.x + w.y * s2.y + w.z * s2.z + w.w * s2.w;
            a3 += w.x * s3.x + w.y * s3.y + w.z * s3.z + w.w * s3.w;
        }
        float bl = b_lin[o];
        out[0][q] = a0 + bl; out[1][q] = a1 + bl;
        out[2][q] = a2 + bl; out[3][q] = a3 + bl;
#pragma unroll
        for (int r = 0; r < 4; ++r) ssq[r] += out[r][q] * out[r][q];
    }

    int lane = tid & 63, wid = tid >> 6;
#pragma unroll
    for (int c = 0; c < 4; ++c) {
        float v = ssq[c];
        for (int o = 32; o > 0; o >>= 1) v += __shfl_down(v, o, 64);
        if (lane == 0) red[c][wid] = v;
    }
    __syncthreads();
    if (tid < 4) tot[tid] = red[tid][0] + red[tid][1] + red[tid][2] + red[tid][3];
    __syncthreads();
#pragma unroll
    for (int r = 0; r < 4; ++r) {
        float norm = sqrtf(tot[r]) + 1e-8f;
#pragma unroll
        for (int q = 0; q < 8; ++q) {
            int o = tid + 256 * q;
            NF[(size_t)(b0 + r) * E_ + o] = out[r][q] / norm;
        }
    }
}

// ---------------- K4: convert W1, W2 to f16 ----------------
__global__ __launch_bounds__(256) void convw_kernel(
        const float* __restrict__ W1, const float* __restrict__ W2,
        _Float16* __restrict__ W1h, _Float16* __restrict__ W2h) {
    int i = blockIdx.x * 256 + threadIdx.x;
    if (i < 131072) {                       // W1: 1024*512/4
        float4 v = *(const float4*)&W1[(size_t)i * 4];
        half4v o = {(_Float16)v.x, (_Float16)v.y, (_Float16)v.z, (_Float16)v.w};
        *(half4v*)&W1h[(size_t)i * 4] = o;
    } else {                                // W2: 2048*1024/4
        int j = i - 131072;
        float4 v = *(const float4*)&W2[(size_t)j * 4];
        half4v o = {(_Float16)v.x, (_Float16)v.y, (_Float16)v.z, (_Float16)v.w};
        *(half4v*)&W2h[(size_t)j * 4] = o;
    }
}

// ---------------- gemm1s: K32-slot 4-ring (r13 proven), + fused BN-stats ----------------
__global__ __launch_bounds__(512, 2) void gemm1s(
        const _Float16* __restrict__ A, const _Float16* __restrict__ Bm,
        const float* __restrict__ bias, _Float16* __restrict__ Cf16,
        double* __restrict__ stats) {
    constexpr int KA = 512, NS = 16, NBX = 4;
    __shared__ _Float16 Sl[4][14336];       // slot: A [4kg][192][8] | B [4kg][256][8]
    int tid = threadIdx.x;
    int ln = tid & 63, w = tid >> 6;
    int wr = w >> 2, wc = w & 3;
    int rid = blockIdx.x;
    int q = rid >> 3;
    int bx = q & (NBX - 1);
    int by = ((q / NBX) << 3) | (rid & 7);
    int n0 = bx * 256, m0 = by * 192;

    bool isA = (w < 4);
    const _Float16* sg[4];
    int ld[4];
    if (isA) {
#pragma unroll
        for (int i = 0; i < 3; ++i) {
            int j = w * 3 + i;
            int u = j * 64 + ln;
            int kg = u / 192, row = u - kg * 192;
            sg[i] = A + (size_t)(m0 + row) * KA + kg * 8;
            ld[i] = j * 512;
        }
        sg[3] = sg[0]; ld[3] = ld[0];
    } else {
#pragma unroll
        for (int i = 0; i < 4; ++i) {
            int j = (w - 4) * 4 + i;
            int u = j * 64 + ln;
            int kg = u >> 8, col = u & 255;
            sg[i] = Bm + (size_t)(n0 + col) * KA + kg * 8;
            ld[i] = 6144 + j * 512;
        }
    }

#define CSTAGE(s) { int ko = (s) * 32; _Float16* dst = &Sl[(s) & 3][0];        \
    if (isA) { gll16(sg[0] + ko, dst + ld[0]); gll16(sg[1] + ko, dst + ld[1]); \
               gll16(sg[2] + ko, dst + ld[2]); }                               \
    else     { gll16(sg[0] + ko, dst + ld[0]); gll16(sg[1] + ko, dst + ld[1]); \
               gll16(sg[2] + ko, dst + ld[2]); gll16(sg[3] + ko, dst + ld[3]); } }
#define WAITV(na, nb) { if (isA) asm volatile("s_waitcnt vmcnt(" #na ")" ::: "memory"); \
                        else     asm volatile("s_waitcnt vmcnt(" #nb ")" ::: "memory"); }

    int aofs[6], bofs[4];
#pragma unroll
    for (int f = 0; f < 6; ++f)
        aofs[f] = ((ln >> 4) * 192 + wr * 96 + f * 16 + (ln & 15)) * 8;
#pragma unroll
    for (int n = 0; n < 4; ++n)
        bofs[n] = 6144 + ((ln >> 4) * 256 + wc * 64 + n * 16 + (ln & 15)) * 8;

    floatx4 zero = {0.f, 0.f, 0.f, 0.f};
    floatx4 acc[6][4];
#pragma unroll
    for (int i = 0; i < 6; ++i)
#pragma unroll
        for (int j = 0; j < 4; ++j) acc[i][j] = zero;

    CSTAGE(0); CSTAGE(1); CSTAGE(2);
    WAITV(6, 8);
    __builtin_amdgcn_s_barrier();

    for (int s = 0; s < NS; ++s) {
        const _Float16* SL = &Sl[s & 3][0];
        half8 bv[4], av[6];
#pragma unroll
        for (int n = 0; n < 4; ++n) bv[n] = *(const half8*)&SL[bofs[n]];
#pragma unroll
        for (int f = 0; f < 6; ++f) av[f] = *(const half8*)&SL[aofs[f]];
        if (s + 3 < NS) CSTAGE(s + 3);
        __builtin_amdgcn_sched_barrier(0);
        asm volatile("s_waitcnt lgkmcnt(0)" ::: "memory");
        __builtin_amdgcn_sched_barrier(0);
        __builtin_amdgcn_s_setprio(1);
#pragma unroll
        for (int f = 0; f < 6; ++f)
#pragma unroll
            for (int n = 0; n < 4; ++n)
                acc[f][n] = __builtin_amdgcn_mfma_f32_16x16x32_f16(av[f], bv[n], acc[f][n], 0, 0, 0);
        __builtin_amdgcn_s_setprio(0);
        __builtin_amdgcn_sched_barrier(0);
        if (s + 1 < NS) {
            if (s + 3 < NS)      { WAITV(6, 8); }
            else if (s + 2 < NS) { WAITV(3, 4); }
            else                 { WAITV(0, 0); }
        }
        __builtin_amdgcn_s_barrier();
    }
#undef CSTAGE
#undef WAITV

    // epilogue: C-write + per-column stats over this block's 192 rows
    float cs[4] = {0.f, 0.f, 0.f, 0.f}, cq[4] = {0.f, 0.f, 0.f, 0.f};
#pragma unroll
    for (int f = 0; f < 6; ++f) {
        int row = m0 + wr * 96 + f * 16 + (ln >> 4) * 4;
#pragma unroll
        for (int n = 0; n < 4; ++n) {
            int col = n0 + wc * 64 + n * 16 + (ln & 15);
            float bb = bias[col];
#pragma unroll
            for (int r = 0; r < 4; ++r) {
                float v = acc[f][n][r] + bb;
                Cf16[(size_t)(row + r) * H_ + col] = (_Float16)v;
                cs[n] += v; cq[n] += v * v;
            }
        }
    }
#pragma unroll
    for (int n = 0; n < 4; ++n) {
        cs[n] += __shfl_xor(cs[n], 16); cs[n] += __shfl_xor(cs[n], 32);
        cq[n] += __shfl_xor(cq[n], 16); cq[n] += __shfl_xor(cq[n], 32);
    }
    float* sp = (float*)&Sl[0][0];          // [2 wr][256 col][2]
    __syncthreads();
    if (ln < 16) {
#pragma unroll
        for (int n = 0; n < 4; ++n) {
            int c = wc * 64 + n * 16 + ln;
            sp[(wr * 256 + c) * 2 + 0] = cs[n];
            sp[(wr * 256 + c) * 2 + 1] = cq[n];
        }
    }
    __syncthreads();
    if (tid < 256) {
        float s0 = sp[tid * 2]     + sp[(256 + tid) * 2];
        float q0 = sp[tid * 2 + 1] + sp[(256 + tid) * 2 + 1];
        atomicAdd(&stats[n0 + tid], (double)s0);
        atomicAdd(&stats[H_ + n0 + tid], (double)q0);
    }
}

// ---------------- K7: finalize BN -> f16 scale/shift ----------------
__global__ void finalize_kernel(const double* __restrict__ stats,
                                const float* __restrict__ gamma,
                                const float* __restrict__ beta,
                                _Float16* __restrict__ scsh16) {
    int c = blockIdx.x * 256 + threadIdx.x;
    if (c >= H_) return;
    double mean = stats[c] / (double)M1;
    double var  = stats[H_ + c] / (double)M1 - mean * mean;
    float sc = gamma[c] * (float)(1.0 / sqrt(var + 1e-5));
    float sh = beta[c] - (float)mean * sc;
    scsh16[c] = (_Float16)sc;
    scsh16[H_ + c] = (_Float16)sh;
}

// ======== gemm2f: m201-style 4-phase dbuf2 GEMM + fused BN/ReLU on A + maxpool ========
// K64 tiles (NT=16), dbuf=2 (112 KB). 8 waves (2M x 4N), wave 96x64 = 6x4 frags.
// Phase (mh,kh): 12 MFMA; p0=(0,0) p1=(1,0) p2=(0,1) p3=(1,1); 2 barriers/phase.
// Staging spread: p0: B(T+1,kh0) gll + A_ISSUE(T+2)->regs; p1: B(T+1,kh1) gll;
// p3 tail: A_XFRM(T+1) (BN+ReLU, pk-f16) ds_writes. Counted waits only at
// p1-end (vmcnt 7) and p3-end (vmcnt 5) - never 0 mid-loop. Stream order per
// tile: [Bkh0 2][A 3][Bkh1 2]. A load->XFRM distance = 7 phases >> HBM lat.
__device__ __forceinline__ half8 bnrelu8(half8 h, const _Float16* scp, const _Float16* shp) {
    half8 s = *(const half8*)scp, t = *(const half8*)shp, o;
#pragma unroll
    for (int e = 0; e < 8; ++e) {
        _Float16 v = h[e] * s[e] + t[e];                 // v_pk_fma_f16
        o[e] = (v > (_Float16)0.f) ? v : (_Float16)0.f;  // v_pk_max_f16
    }
    return o;
}

__global__ __launch_bounds__(512, 2) void gemm2f(
        const _Float16* __restrict__ Hb, const _Float16* __restrict__ Bm,
        const _Float16* __restrict__ scsh16, const float* __restrict__ bias,
        const float* __restrict__ NF, float* __restrict__ out) {
    constexpr int KA = 1024, NT = 16, NBX = 8;
    __shared__ _Float16 Sl[2][28672];       // buf: A [8kg][192][8] | B @12288 [8kg][256][8]
    __shared__ _Float16 scL[H_], shL[H_];
    int tid = threadIdx.x;
    int ln = tid & 63, w = tid >> 6;
    int wr = w >> 2, wc = w & 3;
    int rid = blockIdx.x;
    int qq = rid >> 3;
    int bx = qq & (NBX - 1);
    int by = ((qq / NBX) << 3) | (rid & 7);
    int n0 = bx * 256, m0 = by * 192;

    for (int i = tid; i < H_; i += 512) { scL[i] = scsh16[i]; shL[i] = scsh16[H_ + i]; }

    // A: uniform reg-stage, 3 chunks/wave: kg = w, rows i*64+ln
    const _Float16* sgA[3];
    int ldA[3];
#pragma unroll
    for (int i = 0; i < 3; ++i) {
        int row = i * 64 + ln;
        sgA[i] = Hb + (size_t)(m0 + row) * KA + w * 8;   // + T*64
        ldA[i] = (w * 192 + row) * 8;
    }
    // B: uniform gll16, 4 chunks/wave: kh0: c=2w+q (kg=c>>2); kh1: c=16+2w+q
    const _Float16* sgB[4];
    int ldB[4];
#pragma unroll
    for (int q2 = 0; q2 < 4; ++q2) {
        int c = (q2 < 2) ? (2 * w + q2) : (16 + 2 * w + (q2 - 2));
        int kg = c >> 2, col = (c & 3) * 64 + ln;
        sgB[q2] = Bm + (size_t)(n0 + col) * KA + kg * 8; // + T*64
        ldB[q2] = 12288 + (kg * 256 + col) * 8;
    }

#define A_ISSUE(t, Ra, Rb, Rc) { Ra = *(const half8*)(sgA[0] + (size_t)(t) * 64); \
    Rb = *(const half8*)(sgA[1] + (size_t)(t) * 64);                              \
    Rc = *(const half8*)(sgA[2] + (size_t)(t) * 64); }
#define A_XFRM(t, Ra, Rb, Rc) { _Float16* dst = &Sl[(t) & 1][0]; int c0 = (t) * 64 + w * 8; \
    *(half8*)(dst + ldA[0]) = bnrelu8(Ra, &scL[c0], &shL[c0]); \
    *(half8*)(dst + ldA[1]) = bnrelu8(Rb, &scL[c0], &shL[c0]); \
    *(half8*)(dst + ldA[2]) = bnrelu8(Rc, &scL[c0], &shL[c0]); }
#define B_STG0(t) { _Float16* dst = &Sl[(t) & 1][0]; int ko = (t) * 64; \
    gll16(sgB[0] + ko, dst + ldB[0]); gll16(sgB[1] + ko, dst + ldB[1]); }
#define B_STG1(t) { _Float16* dst = &Sl[(t) & 1][0]; int ko = (t) * 64; \
    gll16(sgB[2] + ko, dst + ldB[2]); gll16(sgB[3] + ko, dst + ldB[3]); }

    int aofs[6][2], bofs[4][2];
#pragma unroll
    for (int f = 0; f < 6; ++f)
#pragma unroll
        for (int kh = 0; kh < 2; ++kh)
            aofs[f][kh] = ((kh * 4 + (ln >> 4)) * 192 + wr * 96 + f * 16 + (ln & 15)) * 8;
#pragma unroll
    for (int n = 0; n < 4; ++n)
#pragma unroll
        for (int kh = 0; kh < 2; ++kh)
            bofs[n][kh] = 12288 + ((kh * 4 + (ln >> 4)) * 256 + wc * 64 + n * 16 + (ln & 15)) * 8;

    floatx4 zero = {0.f, 0.f, 0.f, 0.f};
    floatx4 acc[6][4];
#pragma unroll
    for (int i = 0; i < 6; ++i)
#pragma unroll
        for (int j = 0; j < 4; ++j) acc[i][j] = zero;

    half8 e0a, e0b, e0c, o0a, o0b, o0c;     // A regsets (even/odd tile parity)

#define FENCE __builtin_amdgcn_sched_barrier(0)
#define BAR   __builtin_amdgcn_s_barrier()
#define LGKM0 asm volatile("s_waitcnt lgkmcnt(0)" ::: "memory")
#define PH_READA(mh, kh) { av[0] = *(const half8*)&SL[aofs[(mh) * 3 + 0][kh]]; \
    av[1] = *(const half8*)&SL[aofs[(mh) * 3 + 1][kh]]; \
    av[2] = *(const half8*)&SL[aofs[(mh) * 3 + 2][kh]]; }
#define PH_READB(kh) { bv[0] = *(const half8*)&SL[bofs[0][kh]]; bv[1] = *(const half8*)&SL[bofs[1][kh]]; \
    bv[2] = *(const half8*)&SL[bofs[2][kh]]; bv[3] = *(const half8*)&SL[bofs[3][kh]]; }
#define PH_MFMA(mh) { _Pragma("unroll") for (int f3 = 0; f3 < 3; ++f3) \
    _Pragma("unroll") for (int n = 0; n < 4; ++n) \
        acc[(mh) * 3 + f3][n] = __builtin_amdgcn_mfma_f32_16x16x32_f16(av[f3], bv[n], acc[(mh) * 3 + f3][n], 0, 0, 0); }

    // prologue: stage tile 0 fully; A regs for tiles 0 and 1; XFRM(0) -> buf0
    B_STG0(0); B_STG1(0);
    A_ISSUE(0, e0a, e0b, e0c);
    A_ISSUE(1, o0a, o0b, o0c);
    A_XFRM(0, e0a, e0b, e0c);               // implicit vmcnt drains B0 + A0
    LGKM0;                                  // scL + XFRM(0) ds_writes done
    BAR;

#define TILE(T, Ia, Ib, Ic, Xa, Xb, Xc) { \
    const _Float16* SL = &Sl[(T) & 1][0]; \
    half8 av[3], bv[4]; \
    /* p0 (mh0,kh0) */ \
    PH_READA(0, 0); PH_READB(0); \
    if ((T) + 1 < NT) B_STG0((T) + 1); \
    if ((T) + 2 < NT) A_ISSUE((T) + 2, Ia, Ib, Ic); \
    FENCE; BAR; LGKM0; FENCE; \
    __builtin_amdgcn_s_setprio(1); PH_MFMA(0); __builtin_amdgcn_s_setprio(0); FENCE; \
    BAR; \
    /* p1 (mh1,kh0) */ \
    PH_READA(1, 0); \
    if ((T) + 1 < NT) B_STG1((T) + 1); \
    FENCE; BAR; LGKM0; FENCE; \
    __builtin_amdgcn_s_setprio(1); PH_MFMA(1); __builtin_amdgcn_s_setprio(0); FENCE; \
    if ((T) + 2 < NT)      { asm volatile("s_waitcnt vmcnt(7)" ::: "memory"); } \
    else if ((T) + 1 < NT) { asm volatile("s_waitcnt vmcnt(4)" ::: "memory"); } \
    else                   { asm volatile("s_waitcnt vmcnt(0)" ::: "memory"); } \
    BAR; \
    /* p2 (mh0,kh1) */ \
    PH_READA(0, 1); PH_READB(1); \
    FENCE; BAR; LGKM0; FENCE; \
    __builtin_amdgcn_s_setprio(1); PH_MFMA(0); __builtin_amdgcn_s_setprio(0); FENCE; \
    BAR; \
    /* p3 (mh1,kh1) */ \
    PH_READA(1, 1); \
    FENCE; BAR; LGKM0; FENCE; \
    __builtin_amdgcn_s_setprio(1); PH_MFMA(1); __builtin_amdgcn_s_setprio(0); FENCE; \
    if ((T) + 1 < NT) { \
        A_XFRM((T) + 1, Xa, Xb, Xc); \
        if ((T) + 2 < NT) { asm volatile("s_waitcnt vmcnt(5)" ::: "memory"); } \
        else              { asm volatile("s_waitcnt vmcnt(2)" ::: "memory"); } \
    } \
    LGKM0; BAR; \
}

    for (int s = 0; s < NT; s += 2) {
        TILE(s,     e0a, e0b, e0c, o0a, o0b, o0c);  // issue A(s+2)->e, XFRM(s+1)<-o
        TILE(s + 1, o0a, o0b, o0c, e0a, e0b, e0c);  // issue A(s+3)->o, XFRM(s+2)<-e
    }
#undef TILE
#undef PH_READA
#undef PH_READB
#undef PH_MFMA
#undef FENCE
#undef BAR
#undef LGKM0
#undef A_ISSUE
#undef A_XFRM
#undef B_STG0
#undef B_STG1

    // fused maxpool over 96 rows (wave-half wr owns one batch) + bias + NF
    int batch = by * 2 + wr;
#pragma unroll
    for (int n = 0; n < 4; ++n) {
        float m = -3.4e38f;
#pragma unroll
        for (int f = 0; f < 6; ++f)
#pragma unroll
            for (int r = 0; r < 4; ++r) m = fmaxf(m, acc[f][n][r]);
        m = fmaxf(m, __shfl_xor(m, 16));
        m = fmaxf(m, __shfl_xor(m, 32));
        if (ln < 16) {
            int col = n0 + wc * 64 + n * 16 + ln;
            out[(size_t)batch * E_ + col] = m + bias[col] + NF[(size_t)batch * E_ + col];
        }
    }
}

// ---------------- launch ----------------
extern "C" void kernel_launch(void* const* d_in, const int* in_sizes, int n_in,
                              void* d_out, int out_size, void* d_ws, size_t ws_size,
                              hipStream_t stream) {
    (void)in_sizes; (void)n_in; (void)out_size; (void)ws_size;
    const float* base  = (const float*)d_in[0];
    const float* atten = (const float*)d_in[1];
    // d_in[2] = pid: unused (uniform contiguous groups of 4 by construction)
    const float* W_dyn = (const float*)d_in[3];
    const float* b_dyn = (const float*)d_in[4];
    const float* W_lin = (const float*)d_in[5];
    const float* b_lin = (const float*)d_in[6];
    const float* W1    = (const float*)d_in[7];
    const float* b1    = (const float*)d_in[8];
    const float* gamma = (const float*)d_in[9];
    const float* beta  = (const float*)d_in[10];
    const float* W2    = (const float*)d_in[11];
    const float* b2    = (const float*)d_in[12];
    float* out = (float*)d_out;

    char* wsp = (char*)d_ws;
    int*      idx    = (int*)(wsp);                      // 196608 B
    float*    Y      = (float*)(wsp + 196608);           // 786432 B
    float*    NF     = (float*)(wsp + 983040);           // 4 MB
    double*   stats  = (double*)(wsp + 5177344);         // 16 KB
    _Float16* scsh16 = (_Float16*)(wsp + 5193728);       // 4 KB
    _Float16* W1h    = (_Float16*)(wsp + 5201920);       // 1 MB
    _Float16* W2h    = (_Float16*)(wsp + 6250496);       // 4 MB
    _Float16* Xh     = (_Float16*)(wsp + 10444800);      // 49152x512 f16 = 50.3 MB
    _Float16* Hbh    = (_Float16*)(wsp + 60776448);      // 49152x1024 f16 = 100.7 MB
                                                         // total ~154 MiB

    zero_stats_kernel<<<8, 256, 0, stream>>>(stats);
    topk_kernel<<<B_, 256, 0, stream>>>(atten, idx);
    convw_kernel<<<2560, 256, 0, stream>>>(W1, W2, W1h, W2h);
    gather_kernel<<<M1 / 4, 256, 0, stream>>>(base, idx, W_dyn, b_dyn, Xh, Y);
    newfeat_kernel<<<B_ / 4, 256, 0, stream>>>(Y, W_lin, b_lin, NF);
    gemm1s<<<1024, 512, 0, stream>>>(Xh, W1h, b1, Hbh, stats);
    finalize_kernel<<<4, 256, 0, stream>>>(stats, gamma, beta, scsh16);
    gemm2f<<<2048, 512, 0, stream>>>(Hbh, W2h, scsh16, b2, NF, out);
}

// Round 15
// 525.202 us; speedup vs baseline: 1.2162x; 1.2162x over previous
//
#include <hip/hip_runtime.h>
#include <math.h>

#define B_   512
#define N_   193
#define D_   512
#define E_   2048
#define KTOK 96
#define H_   1024
#define M1   (B_ * KTOK)      // 49152
#define KGD  (KTOK * 4)       // 384

typedef _Float16 half8 __attribute__((ext_vector_type(8)));
typedef _Float16 half4v __attribute__((ext_vector_type(4)));
typedef float floatx4 __attribute__((ext_vector_type(4)));

// async global->LDS, 16B per lane; LDS dest = wave-uniform base + lane*16
__device__ __forceinline__ void gll16(const _Float16* g, _Float16* l) {
    __builtin_amdgcn_global_load_lds(
        (const __attribute__((address_space(1))) unsigned int*)(const void*)g,
        (__attribute__((address_space(3))) unsigned int*)(void*)l, 16, 0, 0);
}

// ---------------- K0: zero BN stats ----------------
__global__ void zero_stats_kernel(double* stats) {
    int i = blockIdx.x * 256 + threadIdx.x;
    if (i < 2 * H_) stats[i] = 0.0;
}

// ---------------- K1: exact stable top-k (rank count) ----------------
__global__ void topk_kernel(const float* __restrict__ atten, int* __restrict__ idx) {
    __shared__ float s[N_];
    int b = blockIdx.x;
    const float* row = atten + (size_t)b * N_ * N_;   // atten[b, 0, :]
    for (int i = threadIdx.x; i < N_; i += blockDim.x)
        s[i] = (i == 0) ? -1.0f : row[i];
    __syncthreads();
    for (int i = threadIdx.x; i < N_; i += blockDim.x) {
        float v = s[i];
        int rank = 0;
        for (int j = 0; j < N_; ++j) {
            float u = s[j];
            rank += (u > v) || (u == v && j < i);
        }
        if (rank < KTOK) idx[b * KTOK + rank] = i;
    }
}

// ---------------- K2: gather + l2norm -> Xh (f16) + dyn-proj stage 1 (Y) ----------------
__global__ __launch_bounds__(256) void gather_kernel(
        const float* __restrict__ base, const int* __restrict__ idx,
        const float* __restrict__ W_dyn, const float* __restrict__ b_dyn,
        _Float16* __restrict__ Xh, float* __restrict__ Y) {
    int ln = threadIdx.x & 63, wv = threadIdx.x >> 6;
    int rowid = blockIdx.x * 4 + wv;        // 0..49151 = b*96 + t
    int b = rowid / KTOK, t = rowid - b * KTOK;
    int tok = idx[rowid];
    const float4* src = (const float4*)(base + ((size_t)b * N_ + tok) * D_);
    float4 v0 = src[ln * 2], v1 = src[ln * 2 + 1];

    float vals[5];
    vals[0] = v0.x * v0.x + v0.y * v0.y + v0.z * v0.z + v0.w * v0.w
            + v1.x * v1.x + v1.y * v1.y + v1.z * v1.z + v1.w * v1.w;
#pragma unroll
    for (int r = 0; r < 4; ++r) {
        const float4* wr = (const float4*)(W_dyn + r * D_);
        float4 w0 = wr[ln * 2], w1 = wr[ln * 2 + 1];
        vals[1 + r] = v0.x * w0.x + v0.y * w0.y + v0.z * w0.z + v0.w * w0.w
                    + v1.x * w1.x + v1.y * w1.y + v1.z * w1.z + v1.w * w1.w;
    }
#pragma unroll
    for (int c = 0; c < 5; ++c)
#pragma unroll
        for (int o = 32; o > 0; o >>= 1) vals[c] += __shfl_xor(vals[c], o, 64);

    float inv = 1.0f / (sqrtf(vals[0]) + 1e-8f);
    half8 o8;
    o8[0] = (_Float16)(v0.x * inv); o8[1] = (_Float16)(v0.y * inv);
    o8[2] = (_Float16)(v0.z * inv); o8[3] = (_Float16)(v0.w * inv);
    o8[4] = (_Float16)(v1.x * inv); o8[5] = (_Float16)(v1.y * inv);
    o8[6] = (_Float16)(v1.z * inv); o8[7] = (_Float16)(v1.w * inv);
    *(half8*)&Xh[(size_t)rowid * D_ + ln * 8] = o8;
    if (ln == 0) {
        int g = b >> 2;
        int n = (b & 3) * KTOK + t;
#pragma unroll
        for (int r = 0; r < 4; ++r)
            Y[(size_t)(g * 4 + r) * KGD + n] = vals[1 + r] + b_dyn[r];
    }
}

// ---------------- K3: new_feats = l2norm(Y @ W_lin^T + b_lin) (fp32, small) ----------------
__global__ __launch_bounds__(256) void newfeat_kernel(
        const float* __restrict__ Y, const float* __restrict__ W_lin,
        const float* __restrict__ b_lin, float* __restrict__ NF) {
    __shared__ float sy[4][KGD];
    __shared__ float red[4][4];
    __shared__ float tot[4];
    int b0 = blockIdx.x * 4;
    int tid = threadIdx.x;
    for (int l = tid; l < 4 * KGD; l += 256)
        sy[l / KGD][l % KGD] = Y[(size_t)b0 * KGD + l];
    __syncthreads();

    float out[4][8];
    float ssq[4] = {0.f, 0.f, 0.f, 0.f};
#pragma unroll
    for (int q = 0; q < 8; ++q) {
        int o = tid + 256 * q;
        float a0 = 0.f, a1 = 0.f, a2 = 0.f, a3 = 0.f;
        const float4* wr = (const float4*)(W_lin + (size_t)o * KGD);
        for (int i4 = 0; i4 < KGD / 4; ++i4) {
            float4 w  = wr[i4];
            float4 s0 = *(const float4*)&sy[0][i4 * 4];
            float4 s1 = *(const float4*)&sy[1][i4 * 4];
            float4 s2 = *(const float4*)&sy[2][i4 * 4];
            float4 s3 = *(const float4*)&sy[3][i4 * 4];
            a0 += w.x * s0.x + w.y * s0.y + w.z * s0.z + w.w * s0.w;
            a1 += w.x * s1.x + w.y * s1.y + w.z * s1.z + w.w * s1.w;
            a2 += w.x * s2.x + w.y * s2.y + w.z * s2.z + w.w * s2.w;
            a3 += w.x * s3.x + w.y * s3.y + w.z * s3.z + w.w * s3.w;
        }
        float bl = b_lin[o];
        out[0][q] = a0 + bl; out[1][q] = a1 + bl;
        out[2][q] = a2 + bl; out[3][q] = a3 + bl;
#pragma unroll
        for (int r = 0; r < 4; ++r) ssq[r] += out[r][q] * out[r][q];
    }

    int lane = tid & 63, wid = tid >> 6;
#pragma unroll
    for (int c = 0; c < 4; ++c) {
        float v = ssq[c];
        for (int o = 32; o > 0; o >>= 1) v += __shfl_down(v, o, 64);
        if (lane == 0) red[c][wid] = v;
    }
    __syncthreads();
    if (tid < 4) tot[tid] = red[tid][0] + red[tid][1] + red[tid][2] + red[tid][3];
    __syncthreads();
#pragma unroll
    for (int r = 0; r < 4; ++r) {
        float norm = sqrtf(tot[r]) + 1e-8f;
#pragma unroll
        for (int q = 0; q < 8; ++q) {
            int o = tid + 256 * q;
            NF[(size_t)(b0 + r) * E_ + o] = out[r][q] / norm;
        }
    }
}

// ---------------- K4: convert W1, W2 to f16 ----------------
__global__ __launch_bounds__(256) void convw_kernel(
        const float* __restrict__ W1, const float* __restrict__ W2,
        _Float16* __restrict__ W1h, _Float16* __restrict__ W2h) {
    int i = blockIdx.x * 256 + threadIdx.x;
    if (i < 131072) {                       // W1: 1024*512/4
        float4 v = *(const float4*)&W1[(size_t)i * 4];
        half4v o = {(_Float16)v.x, (_Float16)v.y, (_Float16)v.z, (_Float16)v.w};
        *(half4v*)&W1h[(size_t)i * 4] = o;
    } else {                                // W2: 2048*1024/4
        int j = i - 131072;
        float4 v = *(const float4*)&W2[(size_t)j * 4];
        half4v o = {(_Float16)v.x, (_Float16)v.y, (_Float16)v.z, (_Float16)v.w};
        *(half4v*)&W2h[(size_t)j * 4] = o;
    }
}

// ---------------- gemm1s: K32-slot 4-ring, 1 barrier/slot, + fused BN-stats ----------------
__global__ __launch_bounds__(512, 2) void gemm1s(
        const _Float16* __restrict__ A, const _Float16* __restrict__ Bm,
        const float* __restrict__ bias, _Float16* __restrict__ Cf16,
        double* __restrict__ stats) {
    constexpr int KA = 512, NS = 16, NBX = 4;
    __shared__ _Float16 Sl[4][14336];       // slot: A [4kg][192][8] | B [4kg][256][8]
    int tid = threadIdx.x;
    int ln = tid & 63, w = tid >> 6;
    int wr = w >> 2, wc = w & 3;
    int rid = blockIdx.x;
    int q = rid >> 3;
    int bx = q & (NBX - 1);
    int by = ((q / NBX) << 3) | (rid & 7);
    int n0 = bx * 256, m0 = by * 192;

    bool isA = (w < 4);
    const _Float16* sg[4];
    int ld[4];
    if (isA) {
#pragma unroll
        for (int i = 0; i < 3; ++i) {
            int j = w * 3 + i;
            int u = j * 64 + ln;
            int kg = u / 192, row = u - kg * 192;
            sg[i] = A + (size_t)(m0 + row) * KA + kg * 8;
            ld[i] = j * 512;
        }
        sg[3] = sg[0]; ld[3] = ld[0];
    } else {
#pragma unroll
        for (int i = 0; i < 4; ++i) {
            int j = (w - 4) * 4 + i;
            int u = j * 64 + ln;
            int kg = u >> 8, col = u & 255;
            sg[i] = Bm + (size_t)(n0 + col) * KA + kg * 8;
            ld[i] = 6144 + j * 512;
        }
    }

#define CSTAGE(s) { int ko = (s) * 32; _Float16* dst = &Sl[(s) & 3][0];        \
    if (isA) { gll16(sg[0] + ko, dst + ld[0]); gll16(sg[1] + ko, dst + ld[1]); \
               gll16(sg[2] + ko, dst + ld[2]); }                               \
    else     { gll16(sg[0] + ko, dst + ld[0]); gll16(sg[1] + ko, dst + ld[1]); \
               gll16(sg[2] + ko, dst + ld[2]); gll16(sg[3] + ko, dst + ld[3]); } }
#define WAITV(na, nb) { if (isA) asm volatile("s_waitcnt vmcnt(" #na ")" ::: "memory"); \
                        else     asm volatile("s_waitcnt vmcnt(" #nb ")" ::: "memory"); }

    int aofs[6], bofs[4];
#pragma unroll
    for (int f = 0; f < 6; ++f)
        aofs[f] = ((ln >> 4) * 192 + wr * 96 + f * 16 + (ln & 15)) * 8;
#pragma unroll
    for (int n = 0; n < 4; ++n)
        bofs[n] = 6144 + ((ln >> 4) * 256 + wc * 64 + n * 16 + (ln & 15)) * 8;

    floatx4 zero = {0.f, 0.f, 0.f, 0.f};
    floatx4 acc[6][4];
#pragma unroll
    for (int i = 0; i < 6; ++i)
#pragma unroll
        for (int j = 0; j < 4; ++j) acc[i][j] = zero;

    CSTAGE(0); CSTAGE(1); CSTAGE(2);
    WAITV(6, 8);
    __builtin_amdgcn_s_barrier();

    for (int s = 0; s < NS; ++s) {
        const _Float16* SL = &Sl[s & 3][0];
        half8 bv[4], av[6];
#pragma unroll
        for (int n = 0; n < 4; ++n) bv[n] = *(const half8*)&SL[bofs[n]];
#pragma unroll
        for (int f = 0; f < 6; ++f) av[f] = *(const half8*)&SL[aofs[f]];
        if (s + 3 < NS) CSTAGE(s + 3);
        __builtin_amdgcn_sched_barrier(0);
        asm volatile("s_waitcnt lgkmcnt(0)" ::: "memory");
        __builtin_amdgcn_sched_barrier(0);
        __builtin_amdgcn_s_setprio(1);
#pragma unroll
        for (int f = 0; f < 6; ++f)
#pragma unroll
            for (int n = 0; n < 4; ++n)
                acc[f][n] = __builtin_amdgcn_mfma_f32_16x16x32_f16(av[f], bv[n], acc[f][n], 0, 0, 0);
        __builtin_amdgcn_s_setprio(0);
        __builtin_amdgcn_sched_barrier(0);
        if (s + 1 < NS) {
            if (s + 3 < NS)      { WAITV(6, 8); }
            else if (s + 2 < NS) { WAITV(3, 4); }
            else                 { WAITV(0, 0); }
        }
        __builtin_amdgcn_s_barrier();
    }
#undef CSTAGE
#undef WAITV

    // epilogue: C-write + per-column stats over this block's 192 rows
    float cs[4] = {0.f, 0.f, 0.f, 0.f}, cq[4] = {0.f, 0.f, 0.f, 0.f};
#pragma unroll
    for (int f = 0; f < 6; ++f) {
        int row = m0 + wr * 96 + f * 16 + (ln >> 4) * 4;
#pragma unroll
        for (int n = 0; n < 4; ++n) {
            int col = n0 + wc * 64 + n * 16 + (ln & 15);
            float bb = bias[col];
#pragma unroll
            for (int r = 0; r < 4; ++r) {
                float v = acc[f][n][r] + bb;
                Cf16[(size_t)(row + r) * H_ + col] = (_Float16)v;
                cs[n] += v; cq[n] += v * v;
            }
        }
    }
#pragma unroll
    for (int n = 0; n < 4; ++n) {
        cs[n] += __shfl_xor(cs[n], 16); cs[n] += __shfl_xor(cs[n], 32);
        cq[n] += __shfl_xor(cq[n], 16); cq[n] += __shfl_xor(cq[n], 32);
    }
    float* sp = (float*)&Sl[0][0];          // [2 wr][256 col][2]
    __syncthreads();
    if (ln < 16) {
#pragma unroll
        for (int n = 0; n < 4; ++n) {
            int c = wc * 64 + n * 16 + ln;
            sp[(wr * 256 + c) * 2 + 0] = cs[n];
            sp[(wr * 256 + c) * 2 + 1] = cq[n];
        }
    }
    __syncthreads();
    if (tid < 256) {
        float s0 = sp[tid * 2]     + sp[(256 + tid) * 2];
        float q0 = sp[tid * 2 + 1] + sp[(256 + tid) * 2 + 1];
        atomicAdd(&stats[n0 + tid], (double)s0);
        atomicAdd(&stats[H_ + n0 + tid], (double)q0);
    }
}

// ---------------- K7: finalize BN -> f16 scale/shift ----------------
__global__ void finalize_kernel(const double* __restrict__ stats,
                                const float* __restrict__ gamma,
                                const float* __restrict__ beta,
                                _Float16* __restrict__ scsh16) {
    int c = blockIdx.x * 256 + threadIdx.x;
    if (c >= H_) return;
    double mean = stats[c] / (double)M1;
    double var  = stats[H_ + c] / (double)M1 - mean * mean;
    float sc = gamma[c] * (float)(1.0 / sqrt(var + 1e-5));
    float sh = beta[c] - (float)mean * sc;
    scsh16[c] = (_Float16)sc;
    scsh16[H_ + c] = (_Float16)sh;
}

// ---------------- gemm2f: r13 4-ring GEMM + fused BN/ReLU on A + fused maxpool ----------------
// Best measured config (280 us): K32-slot 4-ring, 1 barrier/slot, counted
// vmcnt never 0 mid-loop, pk-f16 BN transform, XFRM in MFMA shadow (no fence
// between cluster and tail). Pre-MFMA lgkm fence (rule #18) retained.
__device__ __forceinline__ half8 bnrelu8(half8 h, const _Float16* scp, const _Float16* shp) {
    half8 s = *(const half8*)scp, t = *(const half8*)shp, o;
#pragma unroll
    for (int e = 0; e < 8; ++e) {
        _Float16 v = h[e] * s[e] + t[e];                 // v_pk_fma_f16
        o[e] = (v > (_Float16)0.f) ? v : (_Float16)0.f;  // v_pk_max_f16
    }
    return o;
}

__global__ __launch_bounds__(512, 2) void gemm2f(
        const _Float16* __restrict__ Hb, const _Float16* __restrict__ Bm,
        const _Float16* __restrict__ scsh16, const float* __restrict__ bias,
        const float* __restrict__ NF, float* __restrict__ out) {
    constexpr int KA = 1024, NS = 32, NBX = 8;
    __shared__ _Float16 Sl[4][14336];       // slot: A [4kg][192][8] | B [4kg][256][8]
    __shared__ _Float16 scL[H_], shL[H_];
    int tid = threadIdx.x;
    int ln = tid & 63, w = tid >> 6;
    int wr = w >> 2, wc = w & 3;
    int rid = blockIdx.x;
    int qq = rid >> 3;
    int bx = qq & (NBX - 1);
    int by = ((qq / NBX) << 3) | (rid & 7);
    int n0 = bx * 256, m0 = by * 192;
    bool isA = (w < 4);

    for (int i = tid; i < H_; i += 512) { scL[i] = scsh16[i]; shL[i] = scsh16[H_ + i]; }

    const _Float16 *sgA0 = Hb, *sgA1 = Hb, *sgA2 = Hb;
    int ldA0 = 0, ldA1 = 0, ldA2 = 0, kgA0 = 0, kgA1 = 0, kgA2 = 0;
    const _Float16* sgB[4] = {Bm, Bm, Bm, Bm};
    int ldB[4] = {6144, 6144, 6144, 6144};
    if (isA) {
        { int j = w * 3 + 0; int u = j * 64 + ln; kgA0 = u / 192; int row = u - kgA0 * 192;
          sgA0 = Hb + (size_t)(m0 + row) * KA + kgA0 * 8; ldA0 = j * 512; }
        { int j = w * 3 + 1; int u = j * 64 + ln; kgA1 = u / 192; int row = u - kgA1 * 192;
          sgA1 = Hb + (size_t)(m0 + row) * KA + kgA1 * 8; ldA1 = j * 512; }
        { int j = w * 3 + 2; int u = j * 64 + ln; kgA2 = u / 192; int row = u - kgA2 * 192;
          sgA2 = Hb + (size_t)(m0 + row) * KA + kgA2 * 8; ldA2 = j * 512; }
    } else {
#pragma unroll
        for (int i = 0; i < 4; ++i) {
            int j = (w - 4) * 4 + i;
            int u = j * 64 + ln;
            int kg = u >> 8, col = u & 255;
            sgB[i] = Bm + (size_t)(n0 + col) * KA + kg * 8;
            ldB[i] = 6144 + j * 512;
        }
    }

#define A_ISSUE(t, Ra, Rb, Rc) { Ra = *(const half8*)(sgA0 + (size_t)(t) * 32); \
    Rb = *(const half8*)(sgA1 + (size_t)(t) * 32);                              \
    Rc = *(const half8*)(sgA2 + (size_t)(t) * 32); }
#define A_XFRM(t, Ra, Rb, Rc) { _Float16* dst = &Sl[(t) & 3][0]; int c0 = (t) * 32; \
    *(half8*)(dst + ldA0 + ln * 8) = bnrelu8(Ra, &scL[c0 + kgA0 * 8], &shL[c0 + kgA0 * 8]); \
    *(half8*)(dst + ldA1 + ln * 8) = bnrelu8(Rb, &scL[c0 + kgA1 * 8], &shL[c0 + kgA1 * 8]); \
    *(half8*)(dst + ldA2 + ln * 8) = bnrelu8(Rc, &scL[c0 + kgA2 * 8], &shL[c0 + kgA2 * 8]); }
#define B_STAGE(t) { int ko = (t) * 32; _Float16* dst = &Sl[(t) & 3][0]; \
    gll16(sgB[0] + ko, dst + ldB[0]); gll16(sgB[1] + ko, dst + ldB[1]); \
    gll16(sgB[2] + ko, dst + ldB[2]); gll16(sgB[3] + ko, dst + ldB[3]); }

    int aofs[6], bofs[4];
#pragma unroll
    for (int f = 0; f < 6; ++f)
        aofs[f] = ((ln >> 4) * 192 + wr * 96 + f * 16 + (ln & 15)) * 8;
#pragma unroll
    for (int n = 0; n < 4; ++n)
        bofs[n] = 6144 + ((ln >> 4) * 256 + wc * 64 + n * 16 + (ln & 15)) * 8;

    floatx4 zero = {0.f, 0.f, 0.f, 0.f};
    floatx4 acc[6][4];
#pragma unroll
    for (int i = 0; i < 6; ++i)
#pragma unroll
        for (int j = 0; j < 4; ++j) acc[i][j] = zero;

    half8 e0a, e0b, e0c, e1a, e1b, e1c;     // even/odd regsets

    // prologue: scsh visible; A pre-writes slots 0,1 (slot-2 loads in flight); B stages 0-2
    if (isA) { A_ISSUE(0, e0a, e0b, e0c); A_ISSUE(1, e1a, e1b, e1c); }
    else     { B_STAGE(0); B_STAGE(1); B_STAGE(2); }
    asm volatile("s_waitcnt lgkmcnt(0)" ::: "memory");   // scL ds_writes done
    __builtin_amdgcn_s_barrier();
    if (isA) {
        A_XFRM(0, e0a, e0b, e0c);           // compiler waits vmcnt for regs
        A_ISSUE(2, e0a, e0b, e0c);
        A_XFRM(1, e1a, e1b, e1c);
    } else {
        asm volatile("s_waitcnt vmcnt(8)" ::: "memory");
    }
    asm volatile("s_waitcnt lgkmcnt(0)" ::: "memory");
    __builtin_amdgcn_s_barrier();

    // SLOT: Ia..Ic = regset receiving issue of s+3; Xa..Xc = regset (holding
    // s+2 data, issued at s-1) consumed by XFRM(s+2).
#define SLOT(s, Ia, Ib, Ic, Xa, Xb, Xc) {                                       \
    const _Float16* SL = &Sl[(s) & 3][0];                                       \
    half8 bv[4], av[6];                                                         \
    _Pragma("unroll") for (int n = 0; n < 4; ++n) bv[n] = *(const half8*)&SL[bofs[n]]; \
    _Pragma("unroll") for (int f = 0; f < 6; ++f) av[f] = *(const half8*)&SL[aofs[f]]; \
    if ((s) + 3 < NS) { if (isA) { A_ISSUE((s) + 3, Ia, Ib, Ic); } else { B_STAGE((s) + 3); } } \
    __builtin_amdgcn_sched_barrier(0);                                          \
    asm volatile("s_waitcnt lgkmcnt(0)" ::: "memory");                          \
    __builtin_amdgcn_sched_barrier(0);                                          \
    __builtin_amdgcn_s_setprio(1);                                              \
    _Pragma("unroll") for (int f = 0; f < 6; ++f)                               \
        _Pragma("unroll") for (int n = 0; n < 4; ++n)                           \
            acc[f][n] = __builtin_amdgcn_mfma_f32_16x16x32_f16(av[f], bv[n], acc[f][n], 0, 0, 0); \
    __builtin_amdgcn_s_setprio(0);                                              \
    if (isA) {                                                                  \
        if ((s) + 2 < NS) { A_XFRM((s) + 2, Xa, Xb, Xc); }                      \
        asm volatile("s_waitcnt lgkmcnt(0)" ::: "memory");                      \
    } else {                                                                    \
        if ((s) + 3 < NS)      { asm volatile("s_waitcnt vmcnt(8)" ::: "memory"); } \
        else if ((s) + 2 < NS) { asm volatile("s_waitcnt vmcnt(4)" ::: "memory"); } \
        else if ((s) + 1 < NS) { asm volatile("s_waitcnt vmcnt(0)" ::: "memory"); } \
    }                                                                           \
    __builtin_amdgcn_s_barrier();                                               \
}

    for (int s = 0; s < NS; s += 2) {
        SLOT(s,     e1a, e1b, e1c, e0a, e0b, e0c);   // issue s+3 (odd)->e1, xfrm s+2 (even)<-e0
        SLOT(s + 1, e0a, e0b, e0c, e1a, e1b, e1c);   // issue s+4 (even)->e0, xfrm s+3 (odd)<-e1
    }
#undef SLOT
#undef A_ISSUE
#undef A_XFRM
#undef B_STAGE

    // fused maxpool over 96 rows (wave-half wr owns one batch) + bias + NF
    int batch = by * 2 + wr;
#pragma unroll
    for (int n = 0; n < 4; ++n) {
        float m = -3.4e38f;
#pragma unroll
        for (int f = 0; f < 6; ++f)
#pragma unroll
            for (int r = 0; r < 4; ++r) m = fmaxf(m, acc[f][n][r]);
        m = fmaxf(m, __shfl_xor(m, 16));
        m = fmaxf(m, __shfl_xor(m, 32));
        if (ln < 16) {
            int col = n0 + wc * 64 + n * 16 + ln;
            out[(size_t)batch * E_ + col] = m + bias[col] + NF[(size_t)batch * E_ + col];
        }
    }
}

// ---------------- launch ----------------
extern "C" void kernel_launch(void* const* d_in, const int* in_sizes, int n_in,
                              void* d_out, int out_size, void* d_ws, size_t ws_size,
                              hipStream_t stream) {
    (void)in_sizes; (void)n_in; (void)out_size; (void)ws_size;
    const float* base  = (const float*)d_in[0];
    const float* atten = (const float*)d_in[1];
    // d_in[2] = pid: unused (uniform contiguous groups of 4 by construction)
    const float* W_dyn = (const float*)d_in[3];
    const float* b_dyn = (const float*)d_in[4];
    const float* W_lin = (const float*)d_in[5];
    const float* b_lin = (const float*)d_in[6];
    const float* W1    = (const float*)d_in[7];
    const float* b1    = (const float*)d_in[8];
    const float* gamma = (const float*)d_in[9];
    const float* beta  = (const float*)d_in[10];
    const float* W2    = (const float*)d_in[11];
    const float* b2    = (const float*)d_in[12];
    float* out = (float*)d_out;

    char* wsp = (char*)d_ws;
    int*      idx    = (int*)(wsp);                      // 196608 B
    float*    Y      = (float*)(wsp + 196608);           // 786432 B
    float*    NF     = (float*)(wsp + 983040);           // 4 MB
    double*   stats  = (double*)(wsp + 5177344);         // 16 KB
    _Float16* scsh16 = (_Float16*)(wsp + 5193728);       // 4 KB
    _Float16* W1h    = (_Float16*)(wsp + 5201920);       // 1 MB
    _Float16* W2h    = (_Float16*)(wsp + 6250496);       // 4 MB
    _Float16* Xh     = (_Float16*)(wsp + 10444800);      // 49152x512 f16 = 50.3 MB
    _Float16* Hbh    = (_Float16*)(wsp + 60776448);      // 49152x1024 f16 = 100.7 MB
                                                         // total ~154 MiB

    zero_stats_kernel<<<8, 256, 0, stream>>>(stats);
    topk_kernel<<<B_, 256, 0, stream>>>(atten, idx);
    convw_kernel<<<2560, 256, 0, stream>>>(W1, W2, W1h, W2h);
    gather_kernel<<<M1 / 4, 256, 0, stream>>>(base, idx, W_dyn, b_dyn, Xh, Y);
    newfeat_kernel<<<B_ / 4, 256, 0, stream>>>(Y, W_lin, b_lin, NF);
    gemm1s<<<1024, 512, 0, stream>>>(Xh, W1h, b1, Hbh, stats);
    finalize_kernel<<<4, 256, 0, stream>>>(stats, gamma, beta, scsh16);
    gemm2f<<<2048, 512, 0, stream>>>(Hbh, W2h, scsh16, b2, NF, out);
}